// Round 3
// baseline (393.958 us; speedup 1.0000x reference)
//
#include <hip/hip_runtime.h>
#include <hip/hip_cooperative_groups.h>

namespace cg = cooperative_groups;

typedef _Float16 f16x8 __attribute__((ext_vector_type(8)));
typedef float f32x4 __attribute__((ext_vector_type(4)));

// One cooperative kernel: 256 blocks x 512 threads (1 block/CU).
// Each block = 2 sub-blocks of 256 threads; task width = 512.
// Phases separated by grid.sync():
//  1) conv1 (768 tasks) + Wg2->f16-fragment pack (task 768)
//  2) conv2 (288)   3) conv3+meanpool (192)   4) uv f16 (384) + cls head (24)
//  5) relation MFMA core (576, q-split x4)    6) score head -> Pm (144)
//  7) losses (block 0)
__global__ void __launch_bounds__(512) mega_k(
    const float* __restrict__ sx, const int* __restrict__ sy,
    const float* __restrict__ qx, const int* __restrict__ qy,
    const float* __restrict__ k1, const float* __restrict__ bc1,
    const float* __restrict__ k2, const float* __restrict__ bc2,
    const float* __restrict__ k3, const float* __restrict__ bc3,
    const float* __restrict__ Wlog, const float* __restrict__ blog,
    const float* __restrict__ Wg1, const float* __restrict__ bg1,
    const float* __restrict__ Wg2, const float* __restrict__ bg2,
    const float* __restrict__ Wf1, const float* __restrict__ bf1,
    const float* __restrict__ Wf2, const float* __restrict__ bf2,
    float* __restrict__ ws, float* __restrict__ out)
{
    cg::grid_group grid = cg::this_grid();
    __shared__ __align__(16) float smem_all[2][3584];   // 14 KB per sub-block
    const int tid512 = threadIdx.x;
    const int sub = tid512 >> 8;
    const int tid = tid512 & 255;
    float* smem = smem_all[sub];
    const int bid = blockIdx.x;
    const int tb  = bid*2 + sub;     // task id base, width 512

    // workspace layout
    float* feat1 = ws;                         // 786432
    float* feat2 = feat1 + 786432;             // 294912
    float* feat3 = feat2 + 294912;             // 98304
    float* mf    = feat3 + 98304;              // 1536
    float* rv    = mf    + 1536;               // 64 (24 used)
    float* xfp   = rv    + 64;                 // 576*64 = 36864
    float* Pmg   = xfp   + 36864;              // 160 (144 used)
    _Float16* u16 = (_Float16*)(Pmg + 160);    // 196608
    _Float16* v16 = u16 + 196608;              // 196608
    _Float16* W2h = v16 + 196608;              // 8192

    // ---------------- phase 1: conv1 + Wg2 pack (tasks 0..768)
    for (int itr = 0; itr < 2; itr++) {
        int t = itr*512 + tb;
        __syncthreads();
        if (t < 768) {
            int oc = t & 31;
            if (tid < 27) smem[tid] = k1[oc*27 + tid];
            else if (tid == 27) smem[27] = bc1[oc];
        }
        __syncthreads();
        if (t < 768) {
            int n = t >> 5, oc = t & 31;
            int bi = n / 6, si = n % 6;
            const float* inp = (si < 5) ? sx + (size_t)((bi*5+si)*3)*4096
                                        : qx + (size_t)(bi*3)*4096;
            #pragma unroll
            for (int k = 0; k < 4; k++) {
                int idx = tid + 256*k;
                int oy = idx >> 5, ox = idx & 31;
                float acc = smem[27];
                #pragma unroll
                for (int ic = 0; ic < 3; ic++) {
                    const float* ip = inp + ic*4096;
                    #pragma unroll
                    for (int dy = 0; dy < 3; dy++) {
                        int iy = 2*oy + dy;
                        if (iy >= 64) continue;
                        #pragma unroll
                        for (int dx = 0; dx < 3; dx++) {
                            int ix = 2*ox + dx;
                            if (ix >= 64) continue;
                            acc += ip[iy*64+ix] * smem[ic*9 + dy*3 + dx];
                        }
                    }
                }
                feat1[(size_t)(n*32+oc)*1024 + idx] = fmaxf(acc, 0.f);
            }
        } else if (t == 768) {
            // W2h[((kt*4+nt)*64 + lane)*8 + jj] = Wg2[(kt*32+quad*8+jj)*64 + nt*16+col]
            #pragma unroll
            for (int s = 0; s < 4; s++) {
                int slot = tid + 256*s;
                int tile = slot >> 6, lane2 = slot & 63;
                int kt = tile >> 2, nt = tile & 3;
                int quad2 = lane2 >> 4, col2 = lane2 & 15;
                f16x8 tt;
                #pragma unroll
                for (int jj = 0; jj < 8; jj++)
                    tt[jj] = (_Float16)Wg2[(kt*32 + quad2*8 + jj)*64 + nt*16 + col2];
                *(f16x8*)&W2h[slot*8] = tt;
            }
        }
    }
    grid.sync();

    // ---------------- phase 2: conv2 (288 tasks)
    {
        int t = tb;
        bool act = t < 288;
        int n = t / 12, ocg = t % 12;
        if (act) for (int e = tid; e < 1152; e += 256) smem[e] = k2[ocg*1152 + e];
        __syncthreads();
        if (act) {
            int oy = tid >> 4, ox = tid & 15;
            float a0 = bc2[ocg*4+0], a1 = bc2[ocg*4+1], a2 = bc2[ocg*4+2], a3 = bc2[ocg*4+3];
            const float* ib = feat1 + (size_t)n*32768;
            for (int ic = 0; ic < 32; ic++) {
                const float* ip = ib + ic*1024;
                float tap[9];
                #pragma unroll
                for (int dy = 0; dy < 3; dy++)
                    #pragma unroll
                    for (int dx = 0; dx < 3; dx++) {
                        int iy = 2*oy+dy, ix = 2*ox+dx;
                        tap[dy*3+dx] = (iy < 32 && ix < 32) ? ip[iy*32+ix] : 0.f;
                    }
                #pragma unroll
                for (int u2 = 0; u2 < 9; u2++) {
                    a0 += tap[u2]*smem[0*288 + ic*9 + u2];
                    a1 += tap[u2]*smem[1*288 + ic*9 + u2];
                    a2 += tap[u2]*smem[2*288 + ic*9 + u2];
                    a3 += tap[u2]*smem[3*288 + ic*9 + u2];
                }
            }
            size_t ob = (size_t)(n*48 + ocg*4)*256 + tid;
            feat2[ob      ] = fmaxf(a0, 0.f);
            feat2[ob + 256] = fmaxf(a1, 0.f);
            feat2[ob + 512] = fmaxf(a2, 0.f);
            feat2[ob + 768] = fmaxf(a3, 0.f);
        }
    }
    grid.sync();

    // ---------------- phase 3: conv3 + mean-pool (192 tasks)
    {
        int t = tb;
        bool act = t < 192;
        int n = t >> 3, ocg = t & 7;
        if (act) for (int e = tid; e < 3456; e += 256) smem[e] = k3[ocg*3456 + e];
        __syncthreads();
        if (act) {
            int pix = tid & 63, osub = tid >> 6;
            int oy = pix >> 3, ox = pix & 7;
            int ol0 = osub*2;
            float a0 = bc3[ocg*8 + ol0], a1 = bc3[ocg*8 + ol0 + 1];
            const float* ib = feat2 + (size_t)n*12288;
            for (int ic = 0; ic < 48; ic++) {
                const float* ip = ib + ic*256;
                float tap[9];
                #pragma unroll
                for (int dy = 0; dy < 3; dy++)
                    #pragma unroll
                    for (int dx = 0; dx < 3; dx++) {
                        int iy = 2*oy+dy, ix = 2*ox+dx;
                        tap[dy*3+dx] = (iy < 16 && ix < 16) ? ip[iy*16+ix] : 0.f;
                    }
                #pragma unroll
                for (int u2 = 0; u2 < 9; u2++) {
                    a0 += tap[u2]*smem[ ol0   *432 + ic*9 + u2];
                    a1 += tap[u2]*smem[(ol0+1)*432 + ic*9 + u2];
                }
            }
            float r0 = fmaxf(a0, 0.f), r1 = fmaxf(a1, 0.f);
            feat3[(size_t)(n*64 + ocg*8 + ol0  )*64 + pix] = r0;
            feat3[(size_t)(n*64 + ocg*8 + ol0+1)*64 + pix] = r1;
            #pragma unroll
            for (int off = 32; off >= 1; off >>= 1) {
                r0 += __shfl_xor(r0, off, 64);
                r1 += __shfl_xor(r1, off, 64);
            }
            if (pix == 0) {
                mf[n*64 + ocg*8 + ol0    ] = r0 * (1.f/64.f);
                mf[n*64 + ocg*8 + ol0 + 1] = r1 * (1.f/64.f);
            }
        }
    }
    grid.sync();

    // ---------------- phase 4: uv (384 tasks, f16 out) + cls head (24 tasks)
    {
        int t = tb;
        if (t < 384) {
            int bs = t >> 4, pg = t & 15;
            for (int e = tid; e < 264; e += 256) {
                int pl = e / 66, c = e % 66;
                int p = pg*4 + pl;
                float vvv;
                if (c < 64)       vvv = feat3[(size_t)(bs*64 + c)*64 + p];
                else if (c == 64) vvv = (float)(p >> 3) * 0.125f;
                else              vvv = (float)(p & 7) * 0.125f;
                smem[pl*66 + c] = vvv;
            }
        }
        __syncthreads();
        if (t < 384) {
            int bs = t >> 4, pg = t & 15;
            int col = tid & 127;
            bool isV = tid >= 128;
            const float* Wcol = Wg1 + (isV ? 66*128 : 0) + col;
            float b0 = isV ? bg1[col] : 0.f;
            float acc0 = b0, acc1 = b0, acc2 = b0, acc3 = b0;
            for (int c = 0; c < 66; c++) {
                float wv2 = Wcol[c*128];
                acc0 += smem[c]      * wv2;
                acc1 += smem[66+c]   * wv2;
                acc2 += smem[132+c]  * wv2;
                acc3 += smem[198+c]  * wv2;
            }
            _Float16* dst = isV ? v16 : u16;
            size_t base = (size_t)(bs*64 + pg*4)*128 + col;
            dst[base      ] = (_Float16)acc0;
            dst[base + 128] = (_Float16)acc1;
            dst[base + 256] = (_Float16)acc2;
            dst[base + 384] = (_Float16)acc3;
        } else if (t < 408 && tid < 64) {
            int n = t - 384;
            float s = blog[tid];
            for (int c = 0; c < 64; c++) s += mf[n*64 + c] * Wlog[c*64 + tid];
            float mx = s;
            #pragma unroll
            for (int off = 32; off >= 1; off >>= 1) mx = fmaxf(mx, __shfl_xor(mx, off, 64));
            float p = __expf(s - mx);
            float se = p;
            #pragma unroll
            for (int off = 32; off >= 1; off >>= 1) se += __shfl_xor(se, off, 64);
            int bi = n/6, si = n%6;
            int lab = (si < 5) ? sy[bi*5+si] : qy[bi];
            float s_lab = __shfl(s, lab, 64);
            if (tid == 0) rv[n] = -(s_lab - mx - __logf(se));
        }
    }
    grid.sync();

    // ---------------- phase 5: relation MFMA core (576 tasks, q-split x4)
    {
        const int lane = tid & 63, wv = tid >> 6;
        const int col = lane & 15, quad = lane >> 4;
        f16x8 bf[4][4];
        #pragma unroll
        for (int kt = 0; kt < 4; kt++)
            #pragma unroll
            for (int nt = 0; nt < 4; nt++)
                bf[kt][nt] = *(const f16x8*)&W2h[(size_t)(((kt*4+nt)*64) + lane)*8];
        float bgv[4];
        #pragma unroll
        for (int nt = 0; nt < 4; nt++) bgv[nt] = bg2[nt*16 + col];

        for (int itr = 0; itr < 2; itr++) {
            int t = itr*512 + tb;
            bool act = t < 576;
            __syncthreads();
            _Float16* Vsh = (_Float16*)smem;      // 2048 halves
            float* xfred  = smem + 1024;          // 256 floats
            f16x8 uf[4];
            if (act) {
                int cb = t >> 2, qc = t & 3;
                int b = cb / 36, rem = cb % 36;
                int j = rem / 6, i = rem % 6;
                const _Float16* ub = u16 + (size_t)(b*6 + i)*8192;
                const _Float16* vb = v16 + (size_t)(b*6 + j)*8192 + qc*2048;
                *(f16x8*)&Vsh[tid*8] = *(const f16x8*)&vb[tid*8];
                const _Float16* up = ub + (wv*16 + col)*128 + quad*8;
                #pragma unroll
                for (int kt = 0; kt < 4; kt++) uf[kt] = *(const f16x8*)&up[kt*32];
            }
            __syncthreads();
            if (act) {
                float sums[4] = {0.f,0.f,0.f,0.f};
                for (int q = 0; q < 16; q++) {
                    const _Float16* vp = &Vsh[q*128 + quad*8];
                    f32x4 acc[4];
                    #pragma unroll
                    for (int nt = 0; nt < 4; nt++)
                        acc[nt] = (f32x4){bgv[nt], bgv[nt], bgv[nt], bgv[nt]};
                    #pragma unroll
                    for (int kt = 0; kt < 4; kt++) {
                        f16x8 vf = *(const f16x8*)&vp[kt*32];
                        f16x8 af = uf[kt] + vf;
                        af = __builtin_elementwise_max(af, (f16x8){0,0,0,0,0,0,0,0});
                        #pragma unroll
                        for (int nt = 0; nt < 4; nt++)
                            acc[nt] = __builtin_amdgcn_mfma_f32_16x16x32_f16(af, bf[kt][nt], acc[nt], 0, 0, 0);
                    }
                    #pragma unroll
                    for (int nt = 0; nt < 4; nt++)
                        #pragma unroll
                        for (int rr = 0; rr < 4; rr++)
                            sums[nt] += fmaxf(acc[nt][rr], 0.f);
                }
                #pragma unroll
                for (int nt = 0; nt < 4; nt++) {
                    sums[nt] += __shfl_xor(sums[nt], 16, 64);
                    sums[nt] += __shfl_xor(sums[nt], 32, 64);
                }
                if (lane < 16) {
                    #pragma unroll
                    for (int nt = 0; nt < 4; nt++) xfred[wv*64 + nt*16 + lane] = sums[nt];
                }
            }
            __syncthreads();
            if (act && tid < 64)
                xfp[(size_t)t*64 + tid] = xfred[tid] + xfred[64+tid] + xfred[128+tid] + xfred[192+tid];
        }
    }
    grid.sync();

    // ---------------- phase 6: score head -> Pm (144 tasks)
    {
        int t = tb;
        bool act = t < 144;
        if (act && tid < 64) {
            const float* xb = xfp + (size_t)t*256;
            smem[tid] = xb[tid] + xb[64+tid] + xb[128+tid] + xb[192+tid];
        }
        __syncthreads();
        if (act && tid < 16) {
            float s = bf1[tid];
            for (int c = 0; c < 64; c++) s += smem[c]*Wf1[c*16 + tid];
            smem[64 + tid] = fmaxf(s, 0.f);
        }
        __syncthreads();
        if (act && tid == 0) {
            float sc = bf2[0];
            #pragma unroll
            for (int h = 0; h < 16; h++) sc += smem[64+h]*Wf2[h];
            Pmg[t] = 1.f/(1.f + __expf(-sc));
        }
    }
    grid.sync();

    // ---------------- phase 7: losses (block 0)
    if (bid == 0) {
        float* s0   = &smem_all[0][0];
        float* Pmsh = s0;               // 144
        int*   lab  = (int*)(s0 + 144); // 24
        float* red  = s0 + 192;         // 512
        float* ratio= s0 + 704;         // 4
        int tt = tid512;
        if (tt < 144) Pmsh[tt] = Pmg[tt];
        if (tt < 24) { int bi = tt/6, si = tt%6; lab[tt] = (si < 5) ? sy[bi*5+si] : qy[bi]; }
        __syncthreads();
        float e = 0.f;
        if (tt < 144) {
            int b = tt/36, r = tt%36, jj = r/6, ii = r%6;
            float y = (lab[b*6+jj] == lab[b*6+ii]) ? 1.f : 0.f;
            float d = Pmsh[tt] - y;
            e = d*d;
        }
        red[tt] = e;
        __syncthreads();
        for (int s = 256; s > 0; s >>= 1) {
            if (tt < s) red[tt] += red[tt+s];
            __syncthreads();
        }
        if (tt < 4) {
            float s2 = 0.f, a2 = 0.f;
            for (int jj = 0; jj < 6; jj++)
                for (int ii = 0; ii < 6; ii++) {
                    float pa = Pmsh[tt*36 + jj*6 + ii], pb = Pmsh[tt*36 + ii*6 + jj];
                    float sm = 0.5f*(pa+pb), an = 0.5f*(pa-pb);
                    s2 += sm*sm; a2 += an*an;
                }
            float sn = sqrtf(s2), anq = sqrtf(a2);
            ratio[tt] = (sn - anq)/(sn + anq);
        }
        __syncthreads();
        if (tt == 0) {
            float sl = 0.25f*(ratio[0]+ratio[1]+ratio[2]+ratio[3]);
            float euc = red[0] * (1.f/144.f);
            float cs = 0.f;
            for (int k = 0; k < 24; k++) cs += rv[k];
            out[0] = cs * (1.f/24.f);
            out[1] = euc - 0.1f*sl;
            out[2] = sl;
        }
    }
}

extern "C" void kernel_launch(void* const* d_in, const int* in_sizes, int n_in,
                              void* d_out, int out_size, void* d_ws, size_t ws_size,
                              hipStream_t stream) {
    (void)in_sizes; (void)n_in; (void)out_size; (void)ws_size;
    const float* sx   = (const float*)d_in[0];
    const int*   sy   = (const int*)  d_in[1];
    const float* qx   = (const float*)d_in[2];
    const int*   qy   = (const int*)  d_in[3];
    const float* k1   = (const float*)d_in[4];
    const float* bc1  = (const float*)d_in[5];
    const float* k2   = (const float*)d_in[6];
    const float* bc2  = (const float*)d_in[7];
    const float* k3   = (const float*)d_in[8];
    const float* bc3  = (const float*)d_in[9];
    const float* Wlog = (const float*)d_in[10];
    const float* blog = (const float*)d_in[11];
    const float* Wg1  = (const float*)d_in[12];
    const float* bg1  = (const float*)d_in[13];
    const float* Wg2  = (const float*)d_in[14];
    const float* bg2  = (const float*)d_in[15];
    const float* Wf1  = (const float*)d_in[16];
    const float* bf1  = (const float*)d_in[17];
    const float* Wf2  = (const float*)d_in[18];
    const float* bf2  = (const float*)d_in[19];
    float* ws  = (float*)d_ws;
    float* out = (float*)d_out;

    void* args[] = {
        (void*)&sx, (void*)&sy, (void*)&qx, (void*)&qy,
        (void*)&k1, (void*)&bc1, (void*)&k2, (void*)&bc2,
        (void*)&k3, (void*)&bc3, (void*)&Wlog, (void*)&blog,
        (void*)&Wg1, (void*)&bg1, (void*)&Wg2, (void*)&bg2,
        (void*)&Wf1, (void*)&bf1, (void*)&Wf2, (void*)&bf2,
        (void*)&ws, (void*)&out
    };
    hipLaunchCooperativeKernel((void*)mega_k, dim3(256), dim3(512), args, 0, stream);
}

// Round 4
// 299.483 us; speedup vs baseline: 1.3155x; 1.3155x over previous
//
#include <hip/hip_runtime.h>

typedef _Float16 f16x8 __attribute__((ext_vector_type(8)));
typedef float f32x4 __attribute__((ext_vector_type(4)));

#define NBLK 193

__device__ __forceinline__ void gbar(int* fl, int bid, int tid) {
    __syncthreads();
    if (tid == 0) {
        __builtin_amdgcn_fence(__ATOMIC_RELEASE, "agent");
        __hip_atomic_store(&fl[bid], 1, __ATOMIC_RELAXED, __HIP_MEMORY_SCOPE_AGENT);
    }
    if (tid < 64) {
        for (;;) {
            int ok = 1;
            #pragma unroll
            for (int s = 0; s < 4; s++) {
                int idx = tid + 64*s;
                if (idx < NBLK)
                    ok &= (__hip_atomic_load(&fl[idx], __ATOMIC_RELAXED,
                                             __HIP_MEMORY_SCOPE_AGENT) == 1);
            }
            if (__all(ok)) break;
            __builtin_amdgcn_s_sleep(1);
        }
    }
    __syncthreads();
    __builtin_amdgcn_fence(__ATOMIC_ACQUIRE, "agent");
}

// Single launch, 193 blocks x 512 threads, custom flag barriers.
// P1 conv1(192 blk)+pack(1) | B | P2 conv2(144) | B | P3 conv3+mf(96) | B |
// P4 uv(48)+cls(24) | B | P5 rel+head(144)->Pm flags | P6 blk0: wait Pm, loss.
__global__ void __launch_bounds__(512) mega2_k(
    const float* __restrict__ sx, const int* __restrict__ sy,
    const float* __restrict__ qx, const int* __restrict__ qy,
    const float* __restrict__ k1, const float* __restrict__ bc1,
    const float* __restrict__ k2, const float* __restrict__ bc2,
    const float* __restrict__ k3, const float* __restrict__ bc3,
    const float* __restrict__ Wlog, const float* __restrict__ blog,
    const float* __restrict__ Wg1, const float* __restrict__ bg1,
    const float* __restrict__ Wg2, const float* __restrict__ bg2,
    const float* __restrict__ Wf1, const float* __restrict__ bf1,
    const float* __restrict__ Wf2, const float* __restrict__ bf2,
    float* __restrict__ ws, float* __restrict__ out)
{
    __shared__ __align__(16) float smem[4736];
    const int tid = threadIdx.x;          // 0..511
    const int bid = blockIdx.x;           // 0..192

    float* feat1 = ws;                     // 786432
    float* feat2 = feat1 + 786432;         // 294912
    float* feat3 = feat2 + 294912;         // 98304
    float* mf    = feat3 + 98304;          // 1536
    float* rv    = mf + 1536;              // 64
    float* Pmg   = rv + 64;                // 160
    _Float16* u16 = (_Float16*)(Pmg + 160);    // 196608
    _Float16* v16 = u16 + 196608;              // 196608
    _Float16* W2h = v16 + 196608;              // 8192
    int* flagR   = (int*)(W2h + 8192);         // 4*256
    int* flagB   = flagR + 1024;               // 256

    // ================= P1: conv1 (192 blocks, per block: image n, 4 oc) + pack
    if (bid < 192) {
        int n = bid >> 3, ocq = bid & 7;
        int bi = n / 6, si = n % 6;
        const float* inp = (si < 5) ? sx + (size_t)((bi*5+si)*3)*4096
                                    : qx + (size_t)(bi*3)*4096;
        #pragma unroll
        for (int half = 0; half < 2; half++) {
            int px = tid + half*512;
            int oy = px >> 5, ox = px & 31;
            float tap[27];
            #pragma unroll
            for (int ic = 0; ic < 3; ic++)
                #pragma unroll
                for (int dy = 0; dy < 3; dy++)
                    #pragma unroll
                    for (int dx = 0; dx < 3; dx++) {
                        int iy = 2*oy+dy, ix = 2*ox+dx;
                        tap[ic*9+dy*3+dx] = (iy < 64 && ix < 64) ? inp[ic*4096 + iy*64 + ix] : 0.f;
                    }
            #pragma unroll
            for (int l = 0; l < 4; l++) {
                int oc = ocq*4 + l;
                float acc = bc1[oc];
                #pragma unroll
                for (int t = 0; t < 27; t++) acc += tap[t]*k1[oc*27 + t];
                feat1[(size_t)(n*32+oc)*1024 + px] = fmaxf(acc, 0.f);
            }
        }
    } else { // bid == 192: pack Wg2 -> f16 B-fragments
        #pragma unroll
        for (int s = 0; s < 2; s++) {
            int slot = tid + 512*s;            // 0..1023
            int tile = slot >> 6, lane2 = slot & 63;
            int kt = tile >> 2, nt = tile & 3;
            int quad2 = lane2 >> 4, col2 = lane2 & 15;
            f16x8 tt;
            #pragma unroll
            for (int jj = 0; jj < 8; jj++)
                tt[jj] = (_Float16)Wg2[(kt*32 + quad2*8 + jj)*64 + nt*16 + col2];
            *(f16x8*)&W2h[slot*8] = tt;
        }
    }
    gbar(flagR + 0*256, bid, tid);

    // ================= P2: conv2 (144 blocks: 2 images x 4 oc)
    if (bid < 144) {
        int npair = bid / 12, ocg4 = bid % 12;
        int img = npair*2 + (tid >> 8);
        int px = tid & 255;
        int oy = px >> 4, ox = px & 15;
        float a0 = bc2[ocg4*4+0], a1 = bc2[ocg4*4+1], a2 = bc2[ocg4*4+2], a3 = bc2[ocg4*4+3];
        const float* ib = feat1 + (size_t)img*32768;
        for (int ic = 0; ic < 32; ic++) {
            const float* ip = ib + ic*1024;
            float tap[9];
            #pragma unroll
            for (int dy = 0; dy < 3; dy++)
                #pragma unroll
                for (int dx = 0; dx < 3; dx++) {
                    int iy = 2*oy+dy, ix = 2*ox+dx;
                    tap[dy*3+dx] = (iy < 32 && ix < 32) ? ip[iy*32+ix] : 0.f;
                }
            const float* wb = k2 + (size_t)(ocg4*4)*288 + ic*9;
            #pragma unroll
            for (int t = 0; t < 9; t++) {
                a0 += tap[t]*wb[t];
                a1 += tap[t]*wb[288+t];
                a2 += tap[t]*wb[576+t];
                a3 += tap[t]*wb[864+t];
            }
        }
        size_t ob = (size_t)(img*48 + ocg4*4)*256 + px;
        feat2[ob      ] = fmaxf(a0, 0.f);
        feat2[ob + 256] = fmaxf(a1, 0.f);
        feat2[ob + 512] = fmaxf(a2, 0.f);
        feat2[ob + 768] = fmaxf(a3, 0.f);
    }
    gbar(flagR + 1*256, bid, tid);

    // ================= P3: conv3 + mean-pool (96 blocks: 8 images x 2 oc)
    if (bid < 96) {
        int oct = bid >> 5, ocp = bid & 31;
        int oc0 = ocp*2;
        int img = oct*8 + (tid >> 6);
        int px = tid & 63;
        int oy = px >> 3, ox = px & 7;
        float a0 = bc3[oc0], a1 = bc3[oc0+1];
        const float* ib = feat2 + (size_t)img*12288;
        for (int ic = 0; ic < 48; ic++) {
            const float* ip = ib + ic*256;
            float tap[9];
            #pragma unroll
            for (int dy = 0; dy < 3; dy++)
                #pragma unroll
                for (int dx = 0; dx < 3; dx++) {
                    int iy = 2*oy+dy, ix = 2*ox+dx;
                    tap[dy*3+dx] = (iy < 16 && ix < 16) ? ip[iy*16+ix] : 0.f;
                }
            const float* wb = k3 + (size_t)oc0*432 + ic*9;
            #pragma unroll
            for (int t = 0; t < 9; t++) {
                a0 += tap[t]*wb[t];
                a1 += tap[t]*wb[432+t];
            }
        }
        float r0 = fmaxf(a0, 0.f), r1 = fmaxf(a1, 0.f);
        feat3[(size_t)(img*64 + oc0  )*64 + px] = r0;
        feat3[(size_t)(img*64 + oc0+1)*64 + px] = r1;
        #pragma unroll
        for (int off = 32; off >= 1; off >>= 1) {
            r0 += __shfl_xor(r0, off, 64);
            r1 += __shfl_xor(r1, off, 64);
        }
        if (px == 0) {
            mf[img*64 + oc0    ] = r0 * (1.f/64.f);
            mf[img*64 + oc0 + 1] = r1 * (1.f/64.f);
        }
    }
    gbar(flagR + 2*256, bid, tid);

    // ================= P4: uv (48 blocks: image x p-half) + cls (24 blocks)
    if (bid < 48) {
        int bs = bid >> 1, ph = bid & 1;
        int col = tid & 127;
        int sel = (tid >> 7) & 1;          // 0 = u, 1 = v
        int pq  = tid >> 8;                // 0..1
        int pbase = ph*32 + pq*16;
        float acc[16];
        float b0 = sel ? bg1[col] : 0.f;
        #pragma unroll
        for (int p16 = 0; p16 < 16; p16++) acc[p16] = b0;
        for (int c = 0; c < 66; c++) {
            float w = Wg1[(sel*66 + c)*128 + col];
            #pragma unroll
            for (int p16 = 0; p16 < 16; p16++) {
                int p = pbase + p16;
                float a = (c < 64) ? feat3[((size_t)bs*64 + c)*64 + p]
                        : (c == 64 ? (float)(p>>3)*0.125f : (float)(p&7)*0.125f);
                acc[p16] += a * w;
            }
        }
        _Float16* dst = sel ? v16 : u16;
        #pragma unroll
        for (int p16 = 0; p16 < 16; p16++) {
            int p = pbase + p16;
            dst[(size_t)(bs*64 + p)*128 + col] = (_Float16)acc[p16];
        }
    } else if (bid < 72 && tid < 64) {
        int n = bid - 48;
        float s = blog[tid];
        for (int c = 0; c < 64; c++) s += mf[n*64 + c] * Wlog[c*64 + tid];
        float mx = s;
        #pragma unroll
        for (int off = 32; off >= 1; off >>= 1) mx = fmaxf(mx, __shfl_xor(mx, off, 64));
        float p = __expf(s - mx);
        float se = p;
        #pragma unroll
        for (int off = 32; off >= 1; off >>= 1) se += __shfl_xor(se, off, 64);
        int bi = n/6, si = n%6;
        int lab = (si < 5) ? sy[bi*5+si] : qy[bi];
        float s_lab = __shfl(s, lab, 64);
        if (tid == 0) rv[n] = -(s_lab - mx - __logf(se));
    }
    gbar(flagR + 3*256, bid, tid);

    // ================= P5: rel + head (144 blocks, full q=64 per block)
    if (bid < 144) {
        int cb = bid;
        int b = cb / 36, rem = cb % 36;
        int j = rem / 6, i = rem % 6;
        int lane = tid & 63, wv8 = tid >> 6;     // 8 waves
        int col = lane & 15, quad = lane >> 4;
        int qhalf = wv8 >> 2, pw = wv8 & 3;

        _Float16* Vsh = (_Float16*)smem;          // 8192 halves (16 KB)
        float* xfred  = smem + 4096;              // 8*64
        float* xfl    = smem + 4608;              // 64
        float* hidl   = smem + 4672;              // 16

        const _Float16* ub = u16 + (size_t)(b*6 + i)*8192;
        const _Float16* vb = v16 + (size_t)(b*6 + j)*8192;
        *(f16x8*)&Vsh[tid*16]     = *(const f16x8*)&vb[tid*16];
        *(f16x8*)&Vsh[tid*16 + 8] = *(const f16x8*)&vb[tid*16 + 8];

        f16x8 uf[4];
        {
            const _Float16* up = ub + (pw*16 + col)*128 + quad*8;
            #pragma unroll
            for (int kt = 0; kt < 4; kt++) uf[kt] = *(const f16x8*)&up[kt*32];
        }
        f16x8 bf[4][4];
        #pragma unroll
        for (int kt = 0; kt < 4; kt++)
            #pragma unroll
            for (int nt = 0; nt < 4; nt++)
                bf[kt][nt] = *(const f16x8*)&W2h[(size_t)(((kt*4+nt)*64) + lane)*8];
        float bgv[4];
        #pragma unroll
        for (int nt = 0; nt < 4; nt++) bgv[nt] = bg2[nt*16 + col];
        __syncthreads();

        float sums[4] = {0.f,0.f,0.f,0.f};
        for (int qq = 0; qq < 32; qq++) {
            int q = qhalf*32 + qq;
            const _Float16* vp = &Vsh[q*128 + quad*8];
            f32x4 acc[4];
            #pragma unroll
            for (int nt = 0; nt < 4; nt++)
                acc[nt] = (f32x4){bgv[nt], bgv[nt], bgv[nt], bgv[nt]};
            #pragma unroll
            for (int kt = 0; kt < 4; kt++) {
                f16x8 vf = *(const f16x8*)&vp[kt*32];
                f16x8 af = uf[kt] + vf;
                af = __builtin_elementwise_max(af, (f16x8){0,0,0,0,0,0,0,0});
                #pragma unroll
                for (int nt = 0; nt < 4; nt++)
                    acc[nt] = __builtin_amdgcn_mfma_f32_16x16x32_f16(af, bf[kt][nt], acc[nt], 0, 0, 0);
            }
            #pragma unroll
            for (int nt = 0; nt < 4; nt++)
                #pragma unroll
                for (int rr = 0; rr < 4; rr++)
                    sums[nt] += fmaxf(acc[nt][rr], 0.f);
        }
        #pragma unroll
        for (int nt = 0; nt < 4; nt++) {
            sums[nt] += __shfl_xor(sums[nt], 16, 64);
            sums[nt] += __shfl_xor(sums[nt], 32, 64);
        }
        if (lane < 16) {
            #pragma unroll
            for (int nt = 0; nt < 4; nt++) xfred[wv8*64 + nt*16 + lane] = sums[nt];
        }
        __syncthreads();
        if (tid < 64) {
            float x = 0.f;
            #pragma unroll
            for (int w8 = 0; w8 < 8; w8++) x += xfred[w8*64 + tid];
            xfl[tid] = x;
        }
        __syncthreads();
        if (tid < 16) {
            float s = bf1[tid];
            for (int c = 0; c < 64; c++) s += xfl[c]*Wf1[c*16 + tid];
            hidl[tid] = fmaxf(s, 0.f);
        }
        __syncthreads();
        if (tid == 0) {
            float sc = bf2[0];
            #pragma unroll
            for (int h = 0; h < 16; h++) sc += hidl[h]*Wf2[h];
            Pmg[cb] = 1.f/(1.f + __expf(-sc));
            __builtin_amdgcn_fence(__ATOMIC_RELEASE, "agent");
            __hip_atomic_store(&flagB[cb], 1, __ATOMIC_RELAXED, __HIP_MEMORY_SCOPE_AGENT);
        }
    }

    // ================= P6: losses (block 0)
    if (bid == 0) {
        if (tid < 64) {
            for (;;) {
                int ok = 1;
                #pragma unroll
                for (int s = 0; s < 3; s++) {
                    int idx = tid + 64*s;
                    if (idx < 144)
                        ok &= (__hip_atomic_load(&flagB[idx], __ATOMIC_RELAXED,
                                                 __HIP_MEMORY_SCOPE_AGENT) == 1);
                }
                if (__all(ok)) break;
                __builtin_amdgcn_s_sleep(1);
            }
        }
        __syncthreads();
        __builtin_amdgcn_fence(__ATOMIC_ACQUIRE, "agent");

        float* Pmsh = smem;                 // 144
        int*   lab  = (int*)(smem + 160);   // 24
        float* red  = smem + 192;           // 512
        float* ratio= smem + 704;           // 4
        if (tid < 144) Pmsh[tid] = Pmg[tid];
        if (tid < 24) { int bi = tid/6, si = tid%6; lab[tid] = (si < 5) ? sy[bi*5+si] : qy[bi]; }
        __syncthreads();
        float e = 0.f;
        if (tid < 144) {
            int b = tid/36, r = tid%36, jj = r/6, ii = r%6;
            float y = (lab[b*6+jj] == lab[b*6+ii]) ? 1.f : 0.f;
            float d = Pmsh[tid] - y;
            e = d*d;
        }
        red[tid] = e;
        __syncthreads();
        for (int s = 256; s > 0; s >>= 1) {
            if (tid < s) red[tid] += red[tid+s];
            __syncthreads();
        }
        if (tid < 4) {
            float s2 = 0.f, a2 = 0.f;
            for (int jj = 0; jj < 6; jj++)
                for (int ii = 0; ii < 6; ii++) {
                    float pa = Pmsh[tid*36 + jj*6 + ii], pb = Pmsh[tid*36 + ii*6 + jj];
                    float sm = 0.5f*(pa+pb), an = 0.5f*(pa-pb);
                    s2 += sm*sm; a2 += an*an;
                }
            float sn = sqrtf(s2), anq = sqrtf(a2);
            ratio[tid] = (sn - anq)/(sn + anq);
        }
        __syncthreads();
        if (tid == 0) {
            float sl = 0.25f*(ratio[0]+ratio[1]+ratio[2]+ratio[3]);
            float euc = red[0] * (1.f/144.f);
            float cs = 0.f;
            for (int k = 0; k < 24; k++) cs += rv[k];
            out[0] = cs * (1.f/24.f);
            out[1] = euc - 0.1f*sl;
            out[2] = sl;
        }
    }
}

extern "C" void kernel_launch(void* const* d_in, const int* in_sizes, int n_in,
                              void* d_out, int out_size, void* d_ws, size_t ws_size,
                              hipStream_t stream) {
    (void)in_sizes; (void)n_in; (void)out_size; (void)ws_size;
    const float* sx   = (const float*)d_in[0];
    const int*   sy   = (const int*)  d_in[1];
    const float* qx   = (const float*)d_in[2];
    const int*   qy   = (const int*)  d_in[3];
    const float* k1   = (const float*)d_in[4];
    const float* bc1  = (const float*)d_in[5];
    const float* k2   = (const float*)d_in[6];
    const float* bc2  = (const float*)d_in[7];
    const float* k3   = (const float*)d_in[8];
    const float* bc3  = (const float*)d_in[9];
    const float* Wlog = (const float*)d_in[10];
    const float* blog = (const float*)d_in[11];
    const float* Wg1  = (const float*)d_in[12];
    const float* bg1  = (const float*)d_in[13];
    const float* Wg2  = (const float*)d_in[14];
    const float* bg2  = (const float*)d_in[15];
    const float* Wf1  = (const float*)d_in[16];
    const float* bf1  = (const float*)d_in[17];
    const float* Wf2  = (const float*)d_in[18];
    const float* bf2  = (const float*)d_in[19];
    float* ws  = (float*)d_ws;
    float* out = (float*)d_out;

    mega2_k<<<NBLK, 512, 0, stream>>>(sx, sy, qx, qy, k1, bc1, k2, bc2,
                                      k3, bc3, Wlog, blog, Wg1, bg1, Wg2, bg2,
                                      Wf1, bf1, Wf2, bf2, ws, out);
}

// Round 5
// 196.609 us; speedup vs baseline: 2.0038x; 1.5232x over previous
//
#include <hip/hip_runtime.h>

typedef _Float16 f16x8 __attribute__((ext_vector_type(8)));
typedef float f32x4 __attribute__((ext_vector_type(4)));
typedef unsigned u32x4 __attribute__((ext_vector_type(4)));

#define NB 192

// ---- IF-coherent (L1/L2-bypassing) ws accessors: relaxed system-scope atomics.
__device__ __forceinline__ float ldw(const float* p) {
    return __uint_as_float(__hip_atomic_load((unsigned*)p, __ATOMIC_RELAXED,
                                             __HIP_MEMORY_SCOPE_SYSTEM));
}
__device__ __forceinline__ void stw(float* p, float x) {
    __hip_atomic_store((unsigned*)p, __float_as_uint(x), __ATOMIC_RELAXED,
                       __HIP_MEMORY_SCOPE_SYSTEM);
}
__device__ __forceinline__ unsigned ldu(const unsigned* p) {
    return __hip_atomic_load((unsigned*)p, __ATOMIC_RELAXED, __HIP_MEMORY_SCOPE_SYSTEM);
}
__device__ __forceinline__ void stu(unsigned* p, unsigned x) {
    __hip_atomic_store(p, x, __ATOMIC_RELAXED, __HIP_MEMORY_SCOPE_SYSTEM);
}

__device__ __forceinline__ void postf(int* fl, int bid) {
    asm volatile("s_waitcnt vmcnt(0) lgkmcnt(0)" ::: "memory");
    __hip_atomic_store(fl + bid, 1, __ATOMIC_RELAXED, __HIP_MEMORY_SCOPE_SYSTEM);
}
// barrier: syncthreads (drains each wave's vmem) -> tid0 posts -> wave0 polls all.
__device__ __forceinline__ void gbar(int* fl, int bid, int tid) {
    __syncthreads();
    if (tid == 0) postf(fl, bid);
    if (tid < 64) {
        int* p0 = fl + tid;
        for (;;) {
            int ok = (__hip_atomic_load(p0, __ATOMIC_RELAXED, __HIP_MEMORY_SCOPE_SYSTEM) == 1)
                   & (__hip_atomic_load(p0+64, __ATOMIC_RELAXED, __HIP_MEMORY_SCOPE_SYSTEM) == 1)
                   & (__hip_atomic_load(p0+128, __ATOMIC_RELAXED, __HIP_MEMORY_SCOPE_SYSTEM) == 1);
            if (__all(ok)) break;
            __builtin_amdgcn_s_sleep(2);
        }
    }
    __syncthreads();
    asm volatile("" ::: "memory");
}

__global__ void __launch_bounds__(512) mega3_k(
    const float* __restrict__ sx, const int* __restrict__ sy,
    const float* __restrict__ qx, const int* __restrict__ qy,
    const float* __restrict__ k1, const float* __restrict__ bc1,
    const float* __restrict__ k2, const float* __restrict__ bc2,
    const float* __restrict__ k3, const float* __restrict__ bc3,
    const float* __restrict__ Wlog, const float* __restrict__ blog,
    const float* __restrict__ Wg1, const float* __restrict__ bg1,
    const float* __restrict__ Wg2, const float* __restrict__ bg2,
    const float* __restrict__ Wf1, const float* __restrict__ bf1,
    const float* __restrict__ Wf2, const float* __restrict__ bf2,
    float* __restrict__ ws, float* __restrict__ out)
{
    __shared__ __align__(16) float smem[32768];   // 128 KB
    const int tid = threadIdx.x;
    const int bid = blockIdx.x;

    float* feat1 = ws;                      // 786432
    float* feat2 = feat1 + 786432;          // 294912
    float* feat3 = feat2 + 294912;          // 98304
    float* mf    = feat3 + 98304;           // 1536
    float* rv    = mf + 1536;               // 64
    float* Pmg   = rv + 64;                 // 160
    unsigned* U32 = (unsigned*)(Pmg + 160); // 98304 (u: 196608 halves)
    unsigned* V32 = U32 + 98304;            // 98304
    int* flag0 = (int*)(V32 + 98304);       // 4 x 192 + 192
    int* flag1 = flag0 + 192;
    int* flag2 = flag1 + 192;
    int* flag3 = flag2 + 192;
    int* flagB = flag3 + 192;

    // ================= P1: conv1 (192 blocks: img x 8 oc-quads), input cached
    {
        int n = bid >> 3, ocq = bid & 7;
        int bi = n / 6, si = n % 6;
        const float* inp = (si < 5) ? sx + (size_t)((bi*5+si)*3)*4096
                                    : qx + (size_t)(bi*3)*4096;
        #pragma unroll
        for (int half = 0; half < 2; half++) {
            int px = tid + half*512;
            int oy = px >> 5, ox = px & 31;
            float tap[27];
            #pragma unroll
            for (int ic = 0; ic < 3; ic++)
                #pragma unroll
                for (int dy = 0; dy < 3; dy++)
                    #pragma unroll
                    for (int dx = 0; dx < 3; dx++) {
                        int iy = 2*oy+dy, ix = 2*ox+dx;
                        tap[ic*9+dy*3+dx] = (iy < 64 && ix < 64) ? inp[ic*4096 + iy*64 + ix] : 0.f;
                    }
            #pragma unroll
            for (int l = 0; l < 4; l++) {
                int oc = ocq*4 + l;
                float acc = bc1[oc];
                #pragma unroll
                for (int t = 0; t < 27; t++) acc += tap[t]*k1[oc*27 + t];
                stw(&feat1[(size_t)(n*32+oc)*1024 + px], fmaxf(acc, 0.f));
            }
        }
    }
    gbar(flag0, bid, tid);

    // ================= P2: conv2 (144 blocks: img x 6 oc-groups of 8), LDS-staged
    if (bid < 144) {
        int img = bid / 6, ocg = bid % 6;
        for (int k = 0; k < 64; k++) {
            int e = tid + 512*k;
            smem[e] = ldw(&feat1[(size_t)img*32768 + e]);
        }
        __syncthreads();
        int osub = tid >> 8, px = tid & 255;
        int oy = px >> 4, ox = px & 15;
        int ocb = ocg*8 + osub*4;
        float a0 = bc2[ocb], a1 = bc2[ocb+1], a2 = bc2[ocb+2], a3 = bc2[ocb+3];
        for (int ic = 0; ic < 32; ic++) {
            float tap[9];
            #pragma unroll
            for (int dy = 0; dy < 3; dy++)
                #pragma unroll
                for (int dx = 0; dx < 3; dx++) {
                    int iy = 2*oy+dy, ix = 2*ox+dx;
                    tap[dy*3+dx] = (iy < 32 && ix < 32) ? smem[ic*1024 + iy*32 + ix] : 0.f;
                }
            const float* wb = k2 + (size_t)ocb*288 + ic*9;
            #pragma unroll
            for (int t = 0; t < 9; t++) {
                a0 += tap[t]*wb[t];
                a1 += tap[t]*wb[288+t];
                a2 += tap[t]*wb[576+t];
                a3 += tap[t]*wb[864+t];
            }
        }
        size_t ob = (size_t)(img*48 + ocb)*256 + px;
        stw(&feat2[ob      ], fmaxf(a0, 0.f));
        stw(&feat2[ob + 256], fmaxf(a1, 0.f));
        stw(&feat2[ob + 512], fmaxf(a2, 0.f));
        stw(&feat2[ob + 768], fmaxf(a3, 0.f));
    }
    gbar(flag1, bid, tid);

    // ================= P3: conv3 + mean-pool (192 blocks: img x 8 oc-groups of 8)
    {
        int img = bid >> 3, ocg = bid & 7;
        __syncthreads();
        for (int k = 0; k < 24; k++) {
            int e = tid + 512*k;
            smem[e] = ldw(&feat2[(size_t)img*12288 + e]);
        }
        __syncthreads();
        int osub = tid >> 6, px = tid & 63;
        int oy = px >> 3, ox = px & 7;
        int oc = ocg*8 + osub;
        float a0 = bc3[oc];
        for (int ic = 0; ic < 48; ic++) {
            const float* wb = k3 + (size_t)oc*432 + ic*9;
            #pragma unroll
            for (int dy = 0; dy < 3; dy++)
                #pragma unroll
                for (int dx = 0; dx < 3; dx++) {
                    int iy = 2*oy+dy, ix = 2*ox+dx;
                    float tv = (iy < 16 && ix < 16) ? smem[ic*256 + iy*16 + ix] : 0.f;
                    a0 += tv * wb[dy*3+dx];
                }
        }
        float r0 = fmaxf(a0, 0.f);
        stw(&feat3[(size_t)(img*64 + oc)*64 + px], r0);
        #pragma unroll
        for (int off = 32; off >= 1; off >>= 1) r0 += __shfl_xor(r0, off, 64);
        if (px == 0) stw(&mf[img*64 + oc], r0 * (1.f/64.f));
    }
    gbar(flag2, bid, tid);

    // ================= P4: uv (48 blocks) + cls (blocks 48..71)
    if (bid < 48) {
        int bs = bid >> 1, ph = bid & 1;
        for (int k = 0; k < 8; k++) {
            int e = tid + 512*k;
            smem[e] = ldw(&feat3[(size_t)bs*4096 + e]);
        }
        __syncthreads();
        int cp = tid & 63;             // col pair: cols 2cp, 2cp+1
        int sel = (tid >> 6) & 1;      // 0=u 1=v
        int pq = tid >> 7;             // 0..3
        int pbase = ph*32 + pq*8;
        float acc0[8], acc1[8];
        float b0 = sel ? bg1[2*cp] : 0.f;
        float b1 = sel ? bg1[2*cp+1] : 0.f;
        #pragma unroll
        for (int k = 0; k < 8; k++) { acc0[k] = b0; acc1[k] = b1; }
        const float* Wc = Wg1 + sel*66*128 + 2*cp;
        for (int c = 0; c < 64; c++) {
            float w0 = Wc[c*128], w1 = Wc[c*128 + 1];
            #pragma unroll
            for (int k = 0; k < 8; k++) {
                float a = smem[c*64 + pbase + k];
                acc0[k] += a*w0; acc1[k] += a*w1;
            }
        }
        #pragma unroll
        for (int c = 64; c < 66; c++) {
            float w0 = Wc[c*128], w1 = Wc[c*128 + 1];
            #pragma unroll
            for (int k = 0; k < 8; k++) {
                int p = pbase + k;
                float a = (c == 64) ? (float)(p>>3)*0.125f : (float)(p&7)*0.125f;
                acc0[k] += a*w0; acc1[k] += a*w1;
            }
        }
        unsigned* dst = sel ? V32 : U32;
        #pragma unroll
        for (int k = 0; k < 8; k++) {
            int p = pbase + k;
            unsigned lo = (unsigned)__builtin_bit_cast(unsigned short, (_Float16)acc0[k]);
            unsigned hi = (unsigned)__builtin_bit_cast(unsigned short, (_Float16)acc1[k]);
            stu(&dst[(size_t)bs*4096 + p*64 + cp], lo | (hi << 16));
        }
    } else if (bid < 72 && tid < 64) {
        int n = bid - 48;
        float s = blog[tid];
        for (int c = 0; c < 64; c++) s += ldw(&mf[n*64 + c]) * Wlog[c*64 + tid];
        float mx = s;
        #pragma unroll
        for (int off = 32; off >= 1; off >>= 1) mx = fmaxf(mx, __shfl_xor(mx, off, 64));
        float p = __expf(s - mx);
        float se = p;
        #pragma unroll
        for (int off = 32; off >= 1; off >>= 1) se += __shfl_xor(se, off, 64);
        int bi = n/6, si = n%6;
        int lab = (si < 5) ? sy[bi*5+si] : qy[bi];
        float s_lab = __shfl(s, lab, 64);
        if (tid == 0) stw(&rv[n], -(s_lab - mx - __logf(se)));
    }
    if (bid >= 144) {           // no P5 work: post and leave
        __syncthreads();
        if (tid == 0) postf(flag3, bid);
        return;
    }
    gbar(flag3, bid, tid);

    // ================= P5: rel + head (blocks 0..143)
    {
        int cb = bid;
        int b = cb / 36, rem = cb % 36;
        int j = rem / 6, i = rem % 6;
        int lane = tid & 63, wv8 = tid >> 6;
        int col = lane & 15, quad = lane >> 4;
        int qhalf = wv8 >> 2, pw = wv8 & 3;

        _Float16* Vsh = (_Float16*)smem;       // 8192 halves
        unsigned* Vsh32 = (unsigned*)smem;     // 4096 u32
        float* xfred = smem + 4096;
        float* xfl   = smem + 4608;
        float* hidl  = smem + 4672;

        int uimg = b*6 + i, vimg = b*6 + j;
        __syncthreads();
        #pragma unroll
        for (int k = 0; k < 8; k++) {
            int e = tid + 512*k;
            Vsh32[e] = ldu(&V32[(size_t)vimg*4096 + e]);
        }
        f16x8 uf[4];
        {
            const unsigned* up = U32 + (size_t)uimg*4096 + (pw*16 + col)*64 + quad*4;
            #pragma unroll
            for (int kt = 0; kt < 4; kt++) {
                u32x4 t;
                #pragma unroll
                for (int r = 0; r < 4; r++) t[r] = ldu(&up[kt*16 + r]);
                uf[kt] = __builtin_bit_cast(f16x8, t);
            }
        }
        f16x8 bf[4][4];
        #pragma unroll
        for (int kt = 0; kt < 4; kt++)
            #pragma unroll
            for (int nt = 0; nt < 4; nt++) {
                f16x8 t;
                #pragma unroll
                for (int jj = 0; jj < 8; jj++)
                    t[jj] = (_Float16)Wg2[(kt*32 + quad*8 + jj)*64 + nt*16 + col];
                bf[kt][nt] = t;
            }
        float bgv[4];
        #pragma unroll
        for (int nt = 0; nt < 4; nt++) bgv[nt] = bg2[nt*16 + col];
        __syncthreads();

        float sums[4] = {0.f,0.f,0.f,0.f};
        for (int qq = 0; qq < 32; qq++) {
            int q = qhalf*32 + qq;
            const _Float16* vp = &Vsh[q*128 + quad*8];
            f32x4 acc[4];
            #pragma unroll
            for (int nt = 0; nt < 4; nt++)
                acc[nt] = (f32x4){bgv[nt], bgv[nt], bgv[nt], bgv[nt]};
            #pragma unroll
            for (int kt = 0; kt < 4; kt++) {
                f16x8 vf = *(const f16x8*)&vp[kt*32];
                f16x8 af = uf[kt] + vf;
                af = __builtin_elementwise_max(af, (f16x8){0,0,0,0,0,0,0,0});
                #pragma unroll
                for (int nt = 0; nt < 4; nt++)
                    acc[nt] = __builtin_amdgcn_mfma_f32_16x16x32_f16(af, bf[kt][nt], acc[nt], 0, 0, 0);
            }
            #pragma unroll
            for (int nt = 0; nt < 4; nt++)
                #pragma unroll
                for (int rr = 0; rr < 4; rr++)
                    sums[nt] += fmaxf(acc[nt][rr], 0.f);
        }
        #pragma unroll
        for (int nt = 0; nt < 4; nt++) {
            sums[nt] += __shfl_xor(sums[nt], 16, 64);
            sums[nt] += __shfl_xor(sums[nt], 32, 64);
        }
        if (lane < 16) {
            #pragma unroll
            for (int nt = 0; nt < 4; nt++) xfred[wv8*64 + nt*16 + lane] = sums[nt];
        }
        __syncthreads();
        if (tid < 64) {
            float x = 0.f;
            #pragma unroll
            for (int w8 = 0; w8 < 8; w8++) x += xfred[w8*64 + tid];
            xfl[tid] = x;
        }
        __syncthreads();
        if (tid < 16) {
            float s = bf1[tid];
            for (int c = 0; c < 64; c++) s += xfl[c]*Wf1[c*16 + tid];
            hidl[tid] = fmaxf(s, 0.f);
        }
        __syncthreads();
        if (tid == 0) {
            float sc = bf2[0];
            #pragma unroll
            for (int h = 0; h < 16; h++) sc += hidl[h]*Wf2[h];
            stw(&Pmg[cb], 1.f/(1.f + __expf(-sc)));
            postf(flagB, cb);
        }
    }

    // ================= P6: losses (block 0)
    if (bid == 0) {
        if (tid < 64) {
            int* p0 = flagB + tid;
            for (;;) {
                int ok = (__hip_atomic_load(p0, __ATOMIC_RELAXED, __HIP_MEMORY_SCOPE_SYSTEM) == 1)
                       & (__hip_atomic_load(p0+64, __ATOMIC_RELAXED, __HIP_MEMORY_SCOPE_SYSTEM) == 1)
                       & ((tid < 16) ? (__hip_atomic_load(p0+128, __ATOMIC_RELAXED, __HIP_MEMORY_SCOPE_SYSTEM) == 1) : 1);
                if (__all(ok)) break;
                __builtin_amdgcn_s_sleep(2);
            }
        }
        __syncthreads();
        asm volatile("" ::: "memory");

        float* Pmsh = smem;
        int*   lab  = (int*)(smem + 160);
        float* red  = smem + 192;
        float* ratio= smem + 768;
        if (tid < 144) Pmsh[tid] = ldw(&Pmg[tid]);
        if (tid < 24) { int bi = tid/6, si = tid%6; lab[tid] = (si < 5) ? sy[bi*5+si] : qy[bi]; }
        __syncthreads();
        float e = 0.f;
        if (tid < 144) {
            int b = tid/36, r = tid%36, jj = r/6, ii = r%6;
            float y = (lab[b*6+jj] == lab[b*6+ii]) ? 1.f : 0.f;
            float d = Pmsh[tid] - y;
            e = d*d;
        }
        red[tid] = e;
        __syncthreads();
        for (int s = 256; s > 0; s >>= 1) {
            if (tid < s) red[tid] += red[tid+s];
            __syncthreads();
        }
        if (tid < 4) {
            float s2 = 0.f, a2 = 0.f;
            for (int jj = 0; jj < 6; jj++)
                for (int ii = 0; ii < 6; ii++) {
                    float pa = Pmsh[tid*36 + jj*6 + ii], pb = Pmsh[tid*36 + ii*6 + jj];
                    float sm = 0.5f*(pa+pb), an = 0.5f*(pa-pb);
                    s2 += sm*sm; a2 += an*an;
                }
            float sn = sqrtf(s2), anq = sqrtf(a2);
            ratio[tid] = (sn - anq)/(sn + anq);
        }
        __syncthreads();
        if (tid == 0) {
            float sl = 0.25f*(ratio[0]+ratio[1]+ratio[2]+ratio[3]);
            float euc = red[0] * (1.f/144.f);
            float cs = 0.f;
            for (int k = 0; k < 24; k++) cs += ldw(&rv[k]);
            out[0] = cs * (1.f/24.f);
            out[1] = euc - 0.1f*sl;
            out[2] = sl;
        }
    }
}

extern "C" void kernel_launch(void* const* d_in, const int* in_sizes, int n_in,
                              void* d_out, int out_size, void* d_ws, size_t ws_size,
                              hipStream_t stream) {
    (void)in_sizes; (void)n_in; (void)out_size; (void)ws_size;
    const float* sx   = (const float*)d_in[0];
    const int*   sy   = (const int*)  d_in[1];
    const float* qx   = (const float*)d_in[2];
    const int*   qy   = (const int*)  d_in[3];
    const float* k1   = (const float*)d_in[4];
    const float* bc1  = (const float*)d_in[5];
    const float* k2   = (const float*)d_in[6];
    const float* bc2  = (const float*)d_in[7];
    const float* k3   = (const float*)d_in[8];
    const float* bc3  = (const float*)d_in[9];
    const float* Wlog = (const float*)d_in[10];
    const float* blog = (const float*)d_in[11];
    const float* Wg1  = (const float*)d_in[12];
    const float* bg1  = (const float*)d_in[13];
    const float* Wg2  = (const float*)d_in[14];
    const float* bg2  = (const float*)d_in[15];
    const float* Wf1  = (const float*)d_in[16];
    const float* bf1  = (const float*)d_in[17];
    const float* Wf2  = (const float*)d_in[18];
    const float* bf2  = (const float*)d_in[19];
    float* ws  = (float*)d_ws;
    float* out = (float*)d_out;

    mega3_k<<<NB, 512, 0, stream>>>(sx, sy, qx, qy, k1, bc1, k2, bc2,
                                    k3, bc3, Wlog, blog, Wg1, bg1, Wg2, bg2,
                                    Wf1, bf1, Wf2, bf2, ws, out);
}